// Round 10
// baseline (315.236 us; speedup 1.0000x reference)
//
#include <hip/hip_runtime.h>
#include <math.h>

#define TS 160
#define FEATD 2048
#define HID 512
#define NC 20
#define NB 8
#define KZ 16
#define NBLK 512

typedef __attribute__((ext_vector_type(8))) short bfrag;
typedef __attribute__((ext_vector_type(4))) float f32x4;

static __device__ __forceinline__ unsigned short f2bf(float f) {
  unsigned int u = __float_as_uint(f);
  unsigned int r = (u + 0x7FFFu + ((u >> 16) & 1u)) >> 16;
  return (unsigned short)r;
}
static __device__ __forceinline__ float bf2f(unsigned short s) {
  return __uint_as_float(((unsigned int)s) << 16);
}
static __device__ __forceinline__ void gload16(const void* g, void* l) {
  __builtin_amdgcn_global_load_lds((const __attribute__((address_space(1))) void*)g,
                                   (__attribute__((address_space(3))) void*)l, 16, 0, 0);
}

// persistent mega-kernel: prep -> conv -> feat_head -> tail with device grid barriers
__global__ __launch_bounds__(256, 2) void k_mega(
    const float* __restrict__ x, const float* __restrict__ w1,
    const float* __restrict__ b1, const float* __restrict__ wc,
    const float* __restrict__ wa, const float* __restrict__ ba,
    unsigned short* __restrict__ xb, unsigned short* __restrict__ wb,
    unsigned short* __restrict__ WT, unsigned short* __restrict__ part,
    float* __restrict__ feat, float* __restrict__ y_atn,
    float* __restrict__ y_class, float* __restrict__ y_fg,
    float* __restrict__ bmn, unsigned* bars) {
  __shared__ __align__(16) char LDS[71680];
  const int tid = threadIdx.x;
  const int bid = blockIdx.x;
  const int wid = tid >> 6, lane = tid & 63;

  auto gridbar = [&](unsigned* c) {
    __syncthreads();
    if (tid == 0) {
      __threadfence();
      __hip_atomic_fetch_add(c, 1u, __ATOMIC_RELEASE, __HIP_MEMORY_SCOPE_AGENT);
      while (__hip_atomic_load(c, __ATOMIC_ACQUIRE, __HIP_MEMORY_SCOPE_AGENT) < NBLK)
        __builtin_amdgcn_s_sleep(2);
      __threadfence();
    }
    __syncthreads();
  };

  // ================= phase 1: prep (grid-stride) =================
  for (int bx = bid; bx < 2413; bx += NBLK) {
    if (bx < 1296) {
      // x -> xb bf16, rows pr=0/161 zero pads
      const int idx = bx * 256 + tid;
      const int c = (idx & 255) * 8;
      const int row = idx >> 8;
      const int b = row / 162, pr = row - b * 162;
      unsigned short* o = xb + (size_t)row * FEATD + c;
      if (pr == 0 || pr == 161) {
        *(uint4*)o = make_uint4(0u, 0u, 0u, 0u);
      } else {
        const float* src = x + ((size_t)(b * TS + pr - 1)) * FEATD + c;
        float4 v0 = *(const float4*)src;
        float4 v1 = *(const float4*)(src + 4);
        unsigned short r[8] = {f2bf(v0.x), f2bf(v0.y), f2bf(v0.z), f2bf(v0.w),
                               f2bf(v1.x), f2bf(v1.y), f2bf(v1.z), f2bf(v1.w)};
        *(uint4*)o = *(const uint4*)r;
      }
    } else if (bx < 1808) {
      // w1 -> wb[tap][h][f] bf16, LDS-staged transpose (one h row)
      float* Ls = (float*)LDS;
      const int h = bx - 1296;
      const float4* src = (const float4*)(w1 + (size_t)h * (FEATD * 3));
      for (int e = tid; e < FEATD * 3 / 4; e += 256) ((float4*)Ls)[e] = src[e];
      __syncthreads();
      for (int oc = tid; oc < 768; oc += 256) {
        const int tap = oc >> 8;
        const int f0 = (oc & 255) * 8;
        unsigned short r[8];
        #pragma unroll
        for (int i = 0; i < 8; ++i) r[i] = f2bf(Ls[(f0 + i) * 3 + tap]);
        *(uint4*)&wb[((size_t)tap * HID + h) * FEATD + f0] = *(const uint4*)r;
      }
      __syncthreads();
    } else if (bx < 2408) {
      // WT[g][d+160][tau] bf16, rows d<0 zero
      const int idx = (bx - 1808) * 256 + tid;
      const int tau = idx % 160;
      const int dd = (idx / 160) % 320;
      const int g = idx / (160 * 320);
      float w = 0.f;
      if (dd >= 160) {
        const int d = dd - 160;
        const int k0 = (g == 0) ? 0 : (g == 1 ? 8 : 24);
        const int k1 = (g == 0) ? 8 : (g == 1 ? 24 : 32);
        for (int k = k0; k < k1; ++k) {
          float p = (float)(d * k) / 31.0f;
          float a = fabsf(p - (float)tau);
          w += fmaxf(0.f, 1.f - a);
        }
        w *= (g == 1) ? 0.0625f : 0.125f;
      }
      WT[idx] = f2bf(w);
    } else {
      const int idx = (bx - 2408) * 256 + tid;
      if (idx < NB * TS) y_atn[idx] = ba[0];
    }
  }
  gridbar(&bars[0]);

  // ================= phase 2: conv (512 blocks, 1:1) =================
  {
    const int bb = bid & 7;
    const int hq = (bid >> 3) & 3;
    const int kz = bid >> 5;
    unsigned short* Alds = (unsigned short*)LDS;          // 162*64 = 20736 B
    unsigned short* Blds = (unsigned short*)(LDS + 20736); // 3*128*64 = 49152 B

    const unsigned short* xbb = xb + (size_t)bb * 162 * FEATD;
    f32x4 acc[5][4] = {};
    const int wr = wid >> 1, wc2 = wid & 1;

    for (int s = 0; s < 2; ++s) {
      const int f0 = kz * 128 + s * 64;
      #pragma unroll
      for (int is = 0; is < 5; ++is) {
        const int ci = is * 256 + wid * 64 + lane;
        const int row = ci >> 3, c = ci & 7;
        gload16(xbb + (size_t)row * FEATD + f0 + ((c ^ (row & 7)) << 3),
                (char*)Alds + (size_t)(is * 256 + wid * 64) * 16);
      }
      #pragma unroll
      for (int is = 0; is < 12; ++is) {
        const int ci = is * 256 + wid * 64 + lane;
        const int tap = ci >> 10, rr = (ci >> 3) & 127, c = ci & 7;
        gload16(wb + ((size_t)(tap * HID + hq * 128 + rr)) * FEATD + f0 + ((c ^ (rr & 7)) << 3),
                (char*)Blds + (size_t)(is * 256 + wid * 64) * 16);
      }
      if (tid < 16) {
        const int row = 160 + (tid >> 3), c = tid & 7;
        uint4 v = *(const uint4*)(xbb + (size_t)row * FEATD + f0 + ((c ^ (row & 7)) << 3));
        *(uint4*)((char*)Alds + row * 128 + c * 16) = v;
      }
      __syncthreads();

      #pragma unroll
      for (int tap = 0; tap < 3; ++tap) {
        #pragma unroll
        for (int kk = 0; kk < 2; ++kk) {
          const int cc = kk * 4 + (lane >> 4);
          bfrag bfr[4];
          #pragma unroll
          for (int nf = 0; nf < 4; ++nf) {
            const int hh = wc2 * 64 + nf * 16 + (lane & 15);
            bfr[nf] = *(const bfrag*)((char*)Blds + (size_t)(((tap * 128 + hh) * 8) + (cc ^ (hh & 7))) * 16);
          }
          #pragma unroll
          for (int mi = 0; mi < 5; ++mi) {
            const int rr = wr * 80 + mi * 16 + (lane & 15) + tap;
            bfrag af = *(const bfrag*)((char*)Alds + (size_t)((rr * 8) + (cc ^ (rr & 7))) * 16);
            #pragma unroll
            for (int nf = 0; nf < 4; ++nf)
              acc[mi][nf] = __builtin_amdgcn_mfma_f32_16x16x32_bf16(af, bfr[nf], acc[mi][nf], 0, 0, 0);
          }
        }
      }
      __syncthreads();
    }

    unsigned short* pout = part + (size_t)kz * (NB * TS) * HID;
    #pragma unroll
    for (int mi = 0; mi < 5; ++mi) {
      const int r0 = bb * TS + wr * 80 + mi * 16 + (lane >> 4) * 4;
      #pragma unroll
      for (int nf = 0; nf < 4; ++nf) {
        const int c0 = hq * 128 + wc2 * 64 + nf * 16 + (lane & 15);
        #pragma unroll
        for (int i = 0; i < 4; ++i)
          pout[(size_t)(r0 + i) * HID + c0] = f2bf(acc[mi][nf][i]);
      }
    }
  }
  gridbar(&bars[16]);

  // ================= phase 3: feat_head (blocks 0..319) =================
  if (bid < 320) {
    float* fr = (float*)LDS;              // [4][HID]
    float* sred = (float*)(LDS + 8192);   // [4][4][3]
    const int r0 = bid * 4;
    const int h0 = tid * 2;
    const float bb0 = b1[h0], bb1 = b1[h0 + 1];
    const float wa0 = wa[h0 * 3 + 0], wa1 = wa[h0 * 3 + 1], wa2 = wa[h0 * 3 + 2];
    const float wa3 = wa[h0 * 3 + 3], wa4 = wa[h0 * 3 + 4], wa5 = wa[h0 * 3 + 5];

    #pragma unroll
    for (int r = 0; r < 4; ++r) {
      const int bt = r0 + r;
      float a0 = bb0, a1 = bb1;
      #pragma unroll
      for (int kz2 = 0; kz2 < KZ; ++kz2) {
        unsigned int v = *(const unsigned int*)&part[(size_t)kz2 * (NB * TS * HID) + (size_t)bt * HID + h0];
        a0 += bf2f((unsigned short)(v & 0xffff));
        a1 += bf2f((unsigned short)(v >> 16));
      }
      a0 = fmaxf(a0, 0.f);
      a1 = fmaxf(a1, 0.f);
      float2 fo; fo.x = a0; fo.y = a1;
      *(float2*)&feat[(size_t)bt * HID + h0] = fo;
      fr[r * HID + h0] = a0; fr[r * HID + h0 + 1] = a1;
      float s0 = a0 * wa0 + a1 * wa3;
      float s1 = a0 * wa1 + a1 * wa4;
      float s2 = a0 * wa2 + a1 * wa5;
      #pragma unroll
      for (int off = 32; off; off >>= 1) {
        s0 += __shfl_xor(s0, off);
        s1 += __shfl_xor(s1, off);
        s2 += __shfl_xor(s2, off);
      }
      if (lane == 0) {
        sred[(r * 4 + wid) * 3 + 0] = s0;
        sred[(r * 4 + wid) * 3 + 1] = s1;
        sred[(r * 4 + wid) * 3 + 2] = s2;
      }
    }
    __syncthreads();

    #pragma unroll
    for (int r = 0; r < 4; ++r) {
      const int bt = r0 + r;
      const int b = bt / TS, t = bt - b * TS;
      for (int c = wid; c < NC; c += 4) {
        float p = 0.f;
        #pragma unroll
        for (int i2 = 0; i2 < 8; ++i2) p += fr[r * HID + lane + 64 * i2] * wc[c * HID + lane + 64 * i2];
        #pragma unroll
        for (int off = 32; off; off >>= 1) p += __shfl_xor(p, off);
        if (lane == 0) y_class[((size_t)b * NC + c) * TS + t] = p;
      }
    }
    if (tid < 4) {
      const int bt = r0 + tid;
      const int t = bt % TS;
      float S0 = sred[(tid * 4 + 0) * 3 + 0] + sred[(tid * 4 + 1) * 3 + 0] + sred[(tid * 4 + 2) * 3 + 0] + sred[(tid * 4 + 3) * 3 + 0];
      float S1 = sred[(tid * 4 + 0) * 3 + 1] + sred[(tid * 4 + 1) * 3 + 1] + sred[(tid * 4 + 2) * 3 + 1] + sred[(tid * 4 + 3) * 3 + 1];
      float S2 = sred[(tid * 4 + 0) * 3 + 2] + sred[(tid * 4 + 1) * 3 + 2] + sred[(tid * 4 + 2) * 3 + 2] + sred[(tid * 4 + 3) * 3 + 2];
      atomicAdd(&y_atn[bt], S1);
      if (t < TS - 1) atomicAdd(&y_atn[bt + 1], S0);
      if (t > 0)      atomicAdd(&y_atn[bt - 1], S2);
    }
  }
  gridbar(&bars[32]);

  // ================= phase 4: tail (480 bmn + 8 fg) =================
  if (bid < 480) {
    // bmn: per-(i,g) 160x160x160 bf16 GEMM, D = W·Yᵀ, dwordx4 stores
    char* Alds = LDS;                     // 160 rows x 400 B
    const int g = bid / 160;
    const int i = bid - g * 160;

    const char* wtb = (const char*)WT + (size_t)g * 102400 + (size_t)(160 - i) * 320;
    for (int e = 0; e < 13; ++e) {
      const int ci = e * 256 + tid;
      if (ci < 3200) {
        const int row = ci / 20, c = ci - row * 20;
        const int tb = i + c * 8;
        const float* yr = y_class + (size_t)row * TS;
        unsigned short r8[8];
        #pragma unroll
        for (int k = 0; k < 8; ++k) {
          const int t = tb + k;
          r8[k] = (t < TS) ? f2bf(yr[t]) : (unsigned short)0;
        }
        *(uint4*)(Alds + (size_t)row * 400 + c * 16) = *(const uint4*)r8;
      }
    }
    __syncthreads();

    const int wr = wid >> 1, wcq = wid & 1;   // wr: j-half, wcq: bc-half
    f32x4 acc[5][5] = {};                      // [j-frag][bc-frag]

    #pragma unroll
    for (int ks = 0; ks < 5; ++ks) {
      const int cc = ks * 4 + (lane >> 4);
      bfrag wfr[5];
      #pragma unroll
      for (int jf = 0; jf < 5; ++jf) {
        const int j = wr * 80 + jf * 16 + (lane & 15);
        wfr[jf] = *(const bfrag*)(wtb + (size_t)j * 320 + cc * 16);
      }
      #pragma unroll
      for (int cf = 0; cf < 5; ++cf) {
        const int r = wcq * 80 + cf * 16 + (lane & 15);
        bfrag yf = *(const bfrag*)(Alds + (size_t)r * 400 + cc * 16);
        #pragma unroll
        for (int jf = 0; jf < 5; ++jf)
          acc[jf][cf] = __builtin_amdgcn_mfma_f32_16x16x32_bf16(wfr[jf], yf, acc[jf][cf], 0, 0, 0);
      }
    }

    #pragma unroll
    for (int jf = 0; jf < 5; ++jf) {
      const int j0 = wr * 80 + jf * 16 + (lane >> 4) * 4;
      #pragma unroll
      for (int cf = 0; cf < 5; ++cf) {
        const int bc = wcq * 80 + cf * 16 + (lane & 15);
        const int b = bc / 20, c = bc - b * 20;
        float4 v;
        v.x = acc[jf][cf][0]; v.y = acc[jf][cf][1]; v.z = acc[jf][cf][2]; v.w = acc[jf][cf][3];
        *(float4*)&bmn[(((size_t)(b * 60 + g * 20 + c) * TS) + i) * TS + j0] = v;
      }
    }
  } else if (bid < 488) {
    // attention pooling fg
    const int b = bid - 480;
    float* sig = (float*)LDS;
    float* red = sig + TS;
    float* xfg = red + 8;
    float s = 0.f;
    if (tid < TS) { s = 1.f / (1.f + expf(-y_atn[b * TS + tid])); sig[tid] = s; }
    float r = s;
    #pragma unroll
    for (int off = 32; off; off >>= 1) r += __shfl_xor(r, off);
    if ((tid & 63) == 0) red[tid >> 6] = r;
    __syncthreads();
    const float inv = 1.f / (red[0] + red[1] + red[2] + red[3] + 1e-8f);
    for (int h = tid; h < HID; h += 256) {
      float a = 0.f;
      for (int t = 0; t < TS; ++t) a += sig[t] * feat[((size_t)b * TS + t) * HID + h];
      xfg[h] = a * inv;
    }
    __syncthreads();
    for (int c = wid; c < NC; c += 4) {
      float p = 0.f;
      #pragma unroll
      for (int i2 = 0; i2 < 8; ++i2) {
        int h = lane + 64 * i2;
        p += wc[c * HID + h] * xfg[h];
      }
      #pragma unroll
      for (int off = 32; off; off >>= 1) p += __shfl_xor(p, off);
      if (lane == 0) y_fg[b * NC + c] = p;
    }
  }
}

extern "C" void kernel_launch(void* const* d_in, const int* in_sizes, int n_in,
                              void* d_out, int out_size, void* d_ws, size_t ws_size,
                              hipStream_t stream) {
  const float* x  = (const float*)d_in[0];
  const float* w1 = (const float*)d_in[2];
  const float* b1 = (const float*)d_in[3];
  const float* wc = (const float*)d_in[4];
  const float* wa = (const float*)d_in[5];
  const float* ba = (const float*)d_in[6];

  float* out     = (float*)d_out;
  float* y_class = out;                            // [8,20,160]
  float* y_fg    = out + NB * NC * TS;             // [8,20,1]
  float* bmn     = out + NB * NC * TS + NB * NC;   // [8,60,160,160]

  unsigned short* part = (unsigned short*)d_ws;                           // KZ*1280*512 bf16
  float* feat  = (float*)((char*)d_ws + (size_t)KZ * NB * TS * HID * 2);  // 1280*512 f32
  float* y_atn = feat + NB * TS * HID;                                    // 1280 f32 (pad 2048)
  unsigned short* xb = (unsigned short*)(y_atn + 2048);                   // 8*162*2048 bf16
  unsigned short* wb = xb + (size_t)NB * 162 * FEATD;                     // 3*512*2048 bf16
  unsigned short* WT = wb + (size_t)3 * HID * FEATD;                      // 3*320*160 bf16
  unsigned* bars = (unsigned*)(WT + (size_t)3 * 320 * 160);               // 3 counters, 64B apart

  hipMemsetAsync(bars, 0, 256, stream);
  k_mega<<<NBLK, 256, 0, stream>>>(x, w1, b1, wc, wa, ba,
                                   xb, wb, WT, part, feat, y_atn,
                                   y_class, y_fg, bmn, bars);
}

// Round 11
// 73.581 us; speedup vs baseline: 4.2842x; 4.2842x over previous
//
#include <hip/hip_runtime.h>
#include <math.h>

#define TS 160
#define FEATD 2048
#define HID 512
#define NC 20
#define NB 8
#define KZ 16

typedef __attribute__((ext_vector_type(8))) short bfrag;
typedef __attribute__((ext_vector_type(4))) float f32x4;

static __device__ __forceinline__ unsigned short f2bf(float f) {
  unsigned int u = __float_as_uint(f);
  unsigned int r = (u + 0x7FFFu + ((u >> 16) & 1u)) >> 16;
  return (unsigned short)r;
}
static __device__ __forceinline__ float bf2f(unsigned short s) {
  return __uint_as_float(((unsigned int)s) << 16);
}

static __device__ __forceinline__ void gload16(const void* g, void* l) {
  __builtin_amdgcn_global_load_lds((const __attribute__((address_space(1))) void*)g,
                                   (__attribute__((address_space(3))) void*)l, 16, 0, 0);
}

// ---------- fused prep: cvt x->xb (padded bf16), w1->wb[tap][h][f], build WT, seed y_atn ----------
__global__ __launch_bounds__(256) void k_prep(const float* __restrict__ x,
                                              const float* __restrict__ w1,
                                              const float* __restrict__ ba,
                                              unsigned short* __restrict__ xb,
                                              unsigned short* __restrict__ wb,
                                              unsigned short* __restrict__ WT,
                                              float* __restrict__ y_atn) {
  __shared__ float Ls[FEATD * 3];
  const int tid = threadIdx.x;
  const int bx = blockIdx.x;
  if (bx < 1296) {
    const int idx = bx * 256 + tid;
    const int c = (idx & 255) * 8;
    const int row = idx >> 8;
    const int b = row / 162, pr = row - b * 162;
    unsigned short* o = xb + (size_t)row * FEATD + c;
    if (pr == 0 || pr == 161) {
      *(uint4*)o = make_uint4(0u, 0u, 0u, 0u);
    } else {
      const float* src = x + ((size_t)(b * TS + pr - 1)) * FEATD + c;
      float4 v0 = *(const float4*)src;
      float4 v1 = *(const float4*)(src + 4);
      unsigned short r[8] = {f2bf(v0.x), f2bf(v0.y), f2bf(v0.z), f2bf(v0.w),
                             f2bf(v1.x), f2bf(v1.y), f2bf(v1.z), f2bf(v1.w)};
      *(uint4*)o = *(const uint4*)r;
    }
  } else if (bx < 1808) {
    const int h = bx - 1296;
    const float4* src = (const float4*)(w1 + (size_t)h * (FEATD * 3));
    for (int e = tid; e < FEATD * 3 / 4; e += 256) ((float4*)Ls)[e] = src[e];
    __syncthreads();
    for (int oc = tid; oc < 768; oc += 256) {
      const int tap = oc >> 8;
      const int f0 = (oc & 255) * 8;
      unsigned short r[8];
      #pragma unroll
      for (int i = 0; i < 8; ++i) r[i] = f2bf(Ls[(f0 + i) * 3 + tap]);
      *(uint4*)&wb[((size_t)tap * HID + h) * FEATD + f0] = *(const uint4*)r;
    }
  } else if (bx < 2408) {
    // WT[g][d+160][tau] bf16, rows d<0 zero
    const int idx = (bx - 1808) * 256 + tid;
    const int tau = idx % 160;
    const int dd = (idx / 160) % 320;
    const int g = idx / (160 * 320);
    float w = 0.f;
    if (dd >= 160) {
      const int d = dd - 160;
      const int k0 = (g == 0) ? 0 : (g == 1 ? 8 : 24);
      const int k1 = (g == 0) ? 8 : (g == 1 ? 24 : 32);
      for (int k = k0; k < k1; ++k) {
        float p = (float)(d * k) / 31.0f;
        float a = fabsf(p - (float)tau);
        w += fmaxf(0.f, 1.f - a);
      }
      w *= (g == 1) ? 0.0625f : 0.125f;
    }
    WT[idx] = f2bf(w);
  } else {
    const int idx = (bx - 2408) * 256 + tid;
    if (idx < NB * TS) y_atn[idx] = ba[0];
  }
}

// ---------- conv1d as bf16 MFMA GEMM: wave tile 80x64, block 160x128, K-split 16 ----------
// (R6/R8-proven structure: single-buffered, 72 KB LDS, 2 blocks/CU, plain grid)
__global__ __launch_bounds__(256, 2) void k_conv_mfma(const unsigned short* __restrict__ xb,
                                                      const unsigned short* __restrict__ wb,
                                                      unsigned short* __restrict__ part) {
  const int bb = blockIdx.x;
  const int hq = blockIdx.y;           // h-base = hq*128
  const int kz = blockIdx.z;           // f-base = kz*128
  const int tid = threadIdx.x;
  const int wid = tid >> 6, lane = tid & 63;

  __shared__ unsigned short Alds[162 * 64];      // [row][64 f], chunk-swizzled
  __shared__ unsigned short Blds[3 * 128 * 64];  // [tap][h][64 f], chunk-swizzled

  const unsigned short* xbb = xb + (size_t)bb * 162 * FEATD;

  f32x4 acc[5][4] = {};
  const int wr = wid >> 1, wc = wid & 1;

  for (int s = 0; s < 2; ++s) {
    const int f0 = kz * 128 + s * 64;
    #pragma unroll
    for (int is = 0; is < 5; ++is) {
      const int ci = is * 256 + wid * 64 + lane;
      const int row = ci >> 3, c = ci & 7;
      gload16(xbb + (size_t)row * FEATD + f0 + ((c ^ (row & 7)) << 3),
              (char*)Alds + (size_t)(is * 256 + wid * 64) * 16);
    }
    #pragma unroll
    for (int is = 0; is < 12; ++is) {
      const int ci = is * 256 + wid * 64 + lane;
      const int tap = ci >> 10, rr = (ci >> 3) & 127, c = ci & 7;
      gload16(wb + ((size_t)(tap * HID + hq * 128 + rr)) * FEATD + f0 + ((c ^ (rr & 7)) << 3),
              (char*)Blds + (size_t)(is * 256 + wid * 64) * 16);
    }
    if (tid < 16) {
      const int row = 160 + (tid >> 3), c = tid & 7;
      uint4 v = *(const uint4*)(xbb + (size_t)row * FEATD + f0 + ((c ^ (row & 7)) << 3));
      *(uint4*)((char*)Alds + row * 128 + c * 16) = v;
    }
    __syncthreads();

    #pragma unroll
    for (int tap = 0; tap < 3; ++tap) {
      #pragma unroll
      for (int kk = 0; kk < 2; ++kk) {
        const int cc = kk * 4 + (lane >> 4);
        bfrag bfr[4];
        #pragma unroll
        for (int nf = 0; nf < 4; ++nf) {
          const int hh = wc * 64 + nf * 16 + (lane & 15);
          bfr[nf] = *(const bfrag*)((char*)Blds + (size_t)(((tap * 128 + hh) * 8) + (cc ^ (hh & 7))) * 16);
        }
        #pragma unroll
        for (int mi = 0; mi < 5; ++mi) {
          const int rr = wr * 80 + mi * 16 + (lane & 15) + tap;
          bfrag af = *(const bfrag*)((char*)Alds + (size_t)((rr * 8) + (cc ^ (rr & 7))) * 16);
          #pragma unroll
          for (int nf = 0; nf < 4; ++nf)
            acc[mi][nf] = __builtin_amdgcn_mfma_f32_16x16x32_bf16(af, bfr[nf], acc[mi][nf], 0, 0, 0);
        }
      }
    }
    __syncthreads();
  }

  unsigned short* pout = part + (size_t)kz * (NB * TS) * HID;
  #pragma unroll
  for (int mi = 0; mi < 5; ++mi) {
    const int r0 = bb * TS + wr * 80 + mi * 16 + (lane >> 4) * 4;
    #pragma unroll
    for (int nf = 0; nf < 4; ++nf) {
      const int c0 = hq * 128 + wc * 64 + nf * 16 + (lane & 15);
      #pragma unroll
      for (int i = 0; i < 4; ++i)
        pout[(size_t)(r0 + i) * HID + c0] = f2bf(acc[mi][nf][i]);
    }
  }
}

// ---------- fused: sum partials + bias + relu -> feat; y_class; y_atn tap-scatter ----------
// 4 rows per block (320 blocks)
__global__ __launch_bounds__(256) void k_feat_head(const unsigned short* __restrict__ part,
                                                   const float* __restrict__ b1,
                                                   const float* __restrict__ wc,
                                                   const float* __restrict__ wa,
                                                   float* __restrict__ feat,
                                                   float* __restrict__ y_class,
                                                   float* __restrict__ y_atn) {
  const int r0 = blockIdx.x * 4;        // bt base
  const int tid = threadIdx.x;
  const int wv = tid >> 6, lane = tid & 63;
  __shared__ float fr[4][HID];
  __shared__ float sred[4][4][3];       // [row][wave][tap]
  const int h0 = tid * 2;
  const float bb0 = b1[h0], bb1 = b1[h0 + 1];
  const float wa0 = wa[h0 * 3 + 0], wa1 = wa[h0 * 3 + 1], wa2 = wa[h0 * 3 + 2];
  const float wa3 = wa[h0 * 3 + 3], wa4 = wa[h0 * 3 + 4], wa5 = wa[h0 * 3 + 5];

  #pragma unroll
  for (int r = 0; r < 4; ++r) {
    const int bt = r0 + r;
    float a0 = bb0, a1 = bb1;
    #pragma unroll
    for (int kz = 0; kz < KZ; ++kz) {
      unsigned int v = *(const unsigned int*)&part[(size_t)kz * (NB * TS * HID) + (size_t)bt * HID + h0];
      a0 += bf2f((unsigned short)(v & 0xffff));
      a1 += bf2f((unsigned short)(v >> 16));
    }
    a0 = fmaxf(a0, 0.f);
    a1 = fmaxf(a1, 0.f);
    float2 fo; fo.x = a0; fo.y = a1;
    *(float2*)&feat[(size_t)bt * HID + h0] = fo;
    fr[r][h0] = a0; fr[r][h0 + 1] = a1;
    float s0 = a0 * wa0 + a1 * wa3;
    float s1 = a0 * wa1 + a1 * wa4;
    float s2 = a0 * wa2 + a1 * wa5;
    #pragma unroll
    for (int off = 32; off; off >>= 1) {
      s0 += __shfl_xor(s0, off);
      s1 += __shfl_xor(s1, off);
      s2 += __shfl_xor(s2, off);
    }
    if (lane == 0) { sred[r][wv][0] = s0; sred[r][wv][1] = s1; sred[r][wv][2] = s2; }
  }
  __syncthreads();

  #pragma unroll
  for (int r = 0; r < 4; ++r) {
    const int bt = r0 + r;
    const int b = bt / TS, t = bt - b * TS;
    for (int c = wv; c < NC; c += 4) {
      float p = 0.f;
      #pragma unroll
      for (int i2 = 0; i2 < 8; ++i2) p += fr[r][lane + 64 * i2] * wc[c * HID + lane + 64 * i2];
      #pragma unroll
      for (int off = 32; off; off >>= 1) p += __shfl_xor(p, off);
      if (lane == 0) y_class[((size_t)b * NC + c) * TS + t] = p;
    }
  }
  if (tid < 4) {
    const int bt = r0 + tid;
    const int t = bt % TS;
    float S0 = sred[tid][0][0] + sred[tid][1][0] + sred[tid][2][0] + sred[tid][3][0];
    float S1 = sred[tid][0][1] + sred[tid][1][1] + sred[tid][2][1] + sred[tid][3][1];
    float S2 = sred[tid][0][2] + sred[tid][1][2] + sred[tid][2][2] + sred[tid][3][2];
    atomicAdd(&y_atn[bt], S1);
    if (t < TS - 1) atomicAdd(&y_atn[bt + 1], S0);
    if (t > 0)      atomicAdd(&y_atn[bt - 1], S2);
  }
}

// ---------- fused tail: bmn MFMA (y<3, swapped operands -> dwordx4 stores) + fg (y==3) ----------
__global__ __launch_bounds__(256, 2) void k_tail(const float* __restrict__ y_class,
                                                 const unsigned short* __restrict__ WT,
                                                 const float* __restrict__ feat,
                                                 const float* __restrict__ y_atn,
                                                 const float* __restrict__ wc,
                                                 float* __restrict__ y_fg,
                                                 float* __restrict__ bmn) {
  __shared__ char Alds[64000];          // 160 rows x 400 B (Y bf16)
  const int tid = threadIdx.x;

  if (blockIdx.y == 3) {
    if (blockIdx.x >= NB) return;
    const int b = blockIdx.x;
    float* sig = (float*)Alds;
    float* red = sig + TS;
    float* xfg = red + 8;
    float s = 0.f;
    if (tid < TS) { s = 1.f / (1.f + expf(-y_atn[b * TS + tid])); sig[tid] = s; }
    float r = s;
    #pragma unroll
    for (int off = 32; off; off >>= 1) r += __shfl_xor(r, off);
    if ((tid & 63) == 0) red[tid >> 6] = r;
    __syncthreads();
    const float inv = 1.f / (red[0] + red[1] + red[2] + red[3] + 1e-8f);
    for (int h = tid; h < HID; h += 256) {
      float a = 0.f;
      for (int t = 0; t < TS; ++t) a += sig[t] * feat[((size_t)b * TS + t) * HID + h];
      xfg[h] = a * inv;
    }
    __syncthreads();
    const int wv = tid >> 6, lane = tid & 63;
    for (int c = wv; c < NC; c += 4) {
      float p = 0.f;
      #pragma unroll
      for (int i2 = 0; i2 < 8; ++i2) {
        int h = lane + 64 * i2;
        p += wc[c * HID + h] * xfg[h];
      }
      #pragma unroll
      for (int off = 32; off; off >>= 1) p += __shfl_xor(p, off);
      if (lane == 0) y_fg[b * NC + c] = p;
    }
    return;
  }

  // ---- bmn path: per-(i,g) 160x160x160 bf16 GEMM, D = W·Yᵀ (transposed out) ----
  const int i = blockIdx.x;
  const int g = blockIdx.y;
  const int wid = tid >> 6, lane = tid & 63;

  const char* wtb = (const char*)WT + (size_t)g * 102400 + (size_t)(160 - i) * 320;
  // stage A(=Y): read y_class f32 (L2-hot), cvt bf16, 400-B-stride rows
  for (int e = 0; e < 13; ++e) {
    const int ci = e * 256 + tid;
    if (ci < 3200) {
      const int row = ci / 20, c = ci - row * 20;
      const int tb = i + c * 8;
      const float* yr = y_class + (size_t)row * TS;
      unsigned short r8[8];
      #pragma unroll
      for (int k = 0; k < 8; ++k) {
        const int t = tb + k;
        r8[k] = (t < TS) ? f2bf(yr[t]) : (unsigned short)0;
      }
      *(uint4*)(Alds + (size_t)row * 400 + c * 16) = *(const uint4*)r8;
    }
  }
  __syncthreads();

  const int wr = wid >> 1, wcq = wid & 1;     // wr: j-half, wcq: bc-half
  f32x4 acc[5][5] = {};                        // [j-frag][bc-frag]

  #pragma unroll
  for (int ks = 0; ks < 5; ++ks) {
    const int cc = ks * 4 + (lane >> 4);
    bfrag wfr[5];
    #pragma unroll
    for (int jf = 0; jf < 5; ++jf) {
      const int j = wr * 80 + jf * 16 + (lane & 15);
      wfr[jf] = *(const bfrag*)(wtb + (size_t)j * 320 + cc * 16);
    }
    #pragma unroll
    for (int cf = 0; cf < 5; ++cf) {
      const int r = wcq * 80 + cf * 16 + (lane & 15);
      bfrag yf = *(const bfrag*)(Alds + (size_t)r * 400 + cc * 16);
      #pragma unroll
      for (int jf = 0; jf < 5; ++jf)
        acc[jf][cf] = __builtin_amdgcn_mfma_f32_16x16x32_bf16(wfr[jf], yf, acc[jf][cf], 0, 0, 0);
    }
  }

  // epilogue: D[j][bc] — lane holds 4 consecutive j (reg) for one bc -> dwordx4
  #pragma unroll
  for (int jf = 0; jf < 5; ++jf) {
    const int j0 = wr * 80 + jf * 16 + (lane >> 4) * 4;
    #pragma unroll
    for (int cf = 0; cf < 5; ++cf) {
      const int bc = wcq * 80 + cf * 16 + (lane & 15);
      const int b = bc / 20, c = bc - b * 20;
      float4 v;
      v.x = acc[jf][cf][0]; v.y = acc[jf][cf][1]; v.z = acc[jf][cf][2]; v.w = acc[jf][cf][3];
      *(float4*)&bmn[(((size_t)(b * 60 + g * 20 + c) * TS) + i) * TS + j0] = v;
    }
  }
}

extern "C" void kernel_launch(void* const* d_in, const int* in_sizes, int n_in,
                              void* d_out, int out_size, void* d_ws, size_t ws_size,
                              hipStream_t stream) {
  const float* x  = (const float*)d_in[0];
  const float* w1 = (const float*)d_in[2];
  const float* b1 = (const float*)d_in[3];
  const float* wc = (const float*)d_in[4];
  const float* wa = (const float*)d_in[5];
  const float* ba = (const float*)d_in[6];

  float* out     = (float*)d_out;
  float* y_class = out;                            // [8,20,160]
  float* y_fg    = out + NB * NC * TS;             // [8,20,1]
  float* bmn     = out + NB * NC * TS + NB * NC;   // [8,60,160,160]

  unsigned short* part = (unsigned short*)d_ws;                       // KZ*1280*512 bf16
  float* feat  = (float*)((char*)d_ws + (size_t)KZ * NB * TS * HID * 2);  // 1280*512 f32
  float* y_atn = feat + NB * TS * HID;                                // 1280 f32 (pad 2048)
  unsigned short* xb = (unsigned short*)(y_atn + 2048);               // 8*162*2048 bf16
  unsigned short* wb = xb + (size_t)NB * 162 * FEATD;                 // 3*512*2048 bf16
  unsigned short* WT = wb + (size_t)3 * HID * FEATD;                  // 3*320*160 bf16

  k_prep<<<2413, 256, 0, stream>>>(x, w1, ba, xb, wb, WT, y_atn);
  k_conv_mfma<<<dim3(8, 4, KZ), 256, 0, stream>>>(xb, wb, part);
  k_feat_head<<<NB * TS / 4, 256, 0, stream>>>(part, b1, wc, wa, feat, y_class, y_atn);
  k_tail<<<dim3(160, 4), 256, 0, stream>>>(y_class, WT, feat, y_atn, wc, y_fg, bmn);
}

// Round 13
// 69.795 us; speedup vs baseline: 4.5166x; 1.0542x over previous
//
#include <hip/hip_runtime.h>
#include <math.h>

#define TS 160
#define FEATD 2048
#define HID 512
#define NC 20
#define NB 8
#define KZ 16

typedef __attribute__((ext_vector_type(8))) short bfrag;
typedef __attribute__((ext_vector_type(4))) float f32x4;

static __device__ __forceinline__ unsigned short f2bf(float f) {
  unsigned int u = __float_as_uint(f);
  unsigned int r = (u + 0x7FFFu + ((u >> 16) & 1u)) >> 16;
  return (unsigned short)r;
}
static __device__ __forceinline__ float bf2f(unsigned short s) {
  return __uint_as_float(((unsigned int)s) << 16);
}

static __device__ __forceinline__ void gload16(const void* g, void* l) {
  __builtin_amdgcn_global_load_lds((const __attribute__((address_space(1))) void*)g,
                                   (__attribute__((address_space(3))) void*)l, 16, 0, 0);
}

// ---------- fused prep: cvt x->xb (padded bf16), w1->wb[tap][h][f], build WT, seed y_atn ----------
__global__ __launch_bounds__(256) void k_prep(const float* __restrict__ x,
                                              const float* __restrict__ w1,
                                              const float* __restrict__ ba,
                                              unsigned short* __restrict__ xb,
                                              unsigned short* __restrict__ wb,
                                              unsigned short* __restrict__ WT,
                                              float* __restrict__ y_atn) {
  __shared__ float Ls[FEATD * 3];
  const int tid = threadIdx.x;
  const int bx = blockIdx.x;
  if (bx < 1296) {
    const int idx = bx * 256 + tid;
    const int c = (idx & 255) * 8;
    const int row = idx >> 8;
    const int b = row / 162, pr = row - b * 162;
    unsigned short* o = xb + (size_t)row * FEATD + c;
    if (pr == 0 || pr == 161) {
      *(uint4*)o = make_uint4(0u, 0u, 0u, 0u);
    } else {
      const float* src = x + ((size_t)(b * TS + pr - 1)) * FEATD + c;
      float4 v0 = *(const float4*)src;
      float4 v1 = *(const float4*)(src + 4);
      unsigned short r[8] = {f2bf(v0.x), f2bf(v0.y), f2bf(v0.z), f2bf(v0.w),
                             f2bf(v1.x), f2bf(v1.y), f2bf(v1.z), f2bf(v1.w)};
      *(uint4*)o = *(const uint4*)r;
    }
  } else if (bx < 1808) {
    const int h = bx - 1296;
    const float4* src = (const float4*)(w1 + (size_t)h * (FEATD * 3));
    for (int e = tid; e < FEATD * 3 / 4; e += 256) ((float4*)Ls)[e] = src[e];
    __syncthreads();
    for (int oc = tid; oc < 768; oc += 256) {
      const int tap = oc >> 8;
      const int f0 = (oc & 255) * 8;
      unsigned short r[8];
      #pragma unroll
      for (int i = 0; i < 8; ++i) r[i] = f2bf(Ls[(f0 + i) * 3 + tap]);
      *(uint4*)&wb[((size_t)tap * HID + h) * FEATD + f0] = *(const uint4*)r;
    }
  } else if (bx < 2408) {
    // WT[g][d+160][tau] bf16, rows d<0 zero
    const int idx = (bx - 1808) * 256 + tid;
    const int tau = idx % 160;
    const int dd = (idx / 160) % 320;
    const int g = idx / (160 * 320);
    float w = 0.f;
    if (dd >= 160) {
      const int d = dd - 160;
      const int k0 = (g == 0) ? 0 : (g == 1 ? 8 : 24);
      const int k1 = (g == 0) ? 8 : (g == 1 ? 24 : 32);
      for (int k = k0; k < k1; ++k) {
        float p = (float)(d * k) / 31.0f;
        float a = fabsf(p - (float)tau);
        w += fmaxf(0.f, 1.f - a);
      }
      w *= (g == 1) ? 0.0625f : 0.125f;
    }
    WT[idx] = f2bf(w);
  } else {
    const int idx = (bx - 2408) * 256 + tid;
    if (idx < NB * TS) y_atn[idx] = ba[0];
  }
}

// ---------- conv1d as bf16 MFMA GEMM: wave tile 80x64, block 160x128, K-split 16 ----------
// (R6/R8-proven structure: single-buffered, 72 KB LDS, 2 blocks/CU, plain grid)
__global__ __launch_bounds__(256, 2) void k_conv_mfma(const unsigned short* __restrict__ xb,
                                                      const unsigned short* __restrict__ wb,
                                                      unsigned short* __restrict__ part) {
  const int bb = blockIdx.x;
  const int hq = blockIdx.y;           // h-base = hq*128
  const int kz = blockIdx.z;           // f-base = kz*128
  const int tid = threadIdx.x;
  const int wid = tid >> 6, lane = tid & 63;

  __shared__ unsigned short Alds[162 * 64];      // [row][64 f], chunk-swizzled
  __shared__ unsigned short Blds[3 * 128 * 64];  // [tap][h][64 f], chunk-swizzled

  const unsigned short* xbb = xb + (size_t)bb * 162 * FEATD;

  f32x4 acc[5][4] = {};
  const int wr = wid >> 1, wc = wid & 1;

  for (int s = 0; s < 2; ++s) {
    const int f0 = kz * 128 + s * 64;
    #pragma unroll
    for (int is = 0; is < 5; ++is) {
      const int ci = is * 256 + wid * 64 + lane;
      const int row = ci >> 3, c = ci & 7;
      gload16(xbb + (size_t)row * FEATD + f0 + ((c ^ (row & 7)) << 3),
              (char*)Alds + (size_t)(is * 256 + wid * 64) * 16);
    }
    #pragma unroll
    for (int is = 0; is < 12; ++is) {
      const int ci = is * 256 + wid * 64 + lane;
      const int tap = ci >> 10, rr = (ci >> 3) & 127, c = ci & 7;
      gload16(wb + ((size_t)(tap * HID + hq * 128 + rr)) * FEATD + f0 + ((c ^ (rr & 7)) << 3),
              (char*)Blds + (size_t)(is * 256 + wid * 64) * 16);
    }
    if (tid < 16) {
      const int row = 160 + (tid >> 3), c = tid & 7;
      uint4 v = *(const uint4*)(xbb + (size_t)row * FEATD + f0 + ((c ^ (row & 7)) << 3));
      *(uint4*)((char*)Alds + row * 128 + c * 16) = v;
    }
    __syncthreads();

    #pragma unroll
    for (int tap = 0; tap < 3; ++tap) {
      #pragma unroll
      for (int kk = 0; kk < 2; ++kk) {
        const int cc = kk * 4 + (lane >> 4);
        bfrag bfr[4];
        #pragma unroll
        for (int nf = 0; nf < 4; ++nf) {
          const int hh = wc * 64 + nf * 16 + (lane & 15);
          bfr[nf] = *(const bfrag*)((char*)Blds + (size_t)(((tap * 128 + hh) * 8) + (cc ^ (hh & 7))) * 16);
        }
        #pragma unroll
        for (int mi = 0; mi < 5; ++mi) {
          const int rr = wr * 80 + mi * 16 + (lane & 15) + tap;
          bfrag af = *(const bfrag*)((char*)Alds + (size_t)((rr * 8) + (cc ^ (rr & 7))) * 16);
          #pragma unroll
          for (int nf = 0; nf < 4; ++nf)
            acc[mi][nf] = __builtin_amdgcn_mfma_f32_16x16x32_bf16(af, bfr[nf], acc[mi][nf], 0, 0, 0);
        }
      }
    }
    __syncthreads();
  }

  unsigned short* pout = part + (size_t)kz * (NB * TS) * HID;
  #pragma unroll
  for (int mi = 0; mi < 5; ++mi) {
    const int r0 = bb * TS + wr * 80 + mi * 16 + (lane >> 4) * 4;
    #pragma unroll
    for (int nf = 0; nf < 4; ++nf) {
      const int c0 = hq * 128 + wc * 64 + nf * 16 + (lane & 15);
      #pragma unroll
      for (int i = 0; i < 4; ++i)
        pout[(size_t)(r0 + i) * HID + c0] = f2bf(acc[mi][nf][i]);
    }
  }
}

// ---------- fused: sum partials + bias + relu -> feat; y_class; y_atn tap-scatter ----------
// 4 rows per block (320 blocks)
__global__ __launch_bounds__(256) void k_feat_head(const unsigned short* __restrict__ part,
                                                   const float* __restrict__ b1,
                                                   const float* __restrict__ wc,
                                                   const float* __restrict__ wa,
                                                   float* __restrict__ feat,
                                                   float* __restrict__ y_class,
                                                   float* __restrict__ y_atn) {
  const int r0 = blockIdx.x * 4;        // bt base
  const int tid = threadIdx.x;
  const int wv = tid >> 6, lane = tid & 63;
  __shared__ float fr[4][HID];
  __shared__ float sred[4][4][3];       // [row][wave][tap]
  const int h0 = tid * 2;
  const float bb0 = b1[h0], bb1 = b1[h0 + 1];
  const float wa0 = wa[h0 * 3 + 0], wa1 = wa[h0 * 3 + 1], wa2 = wa[h0 * 3 + 2];
  const float wa3 = wa[h0 * 3 + 3], wa4 = wa[h0 * 3 + 4], wa5 = wa[h0 * 3 + 5];

  #pragma unroll
  for (int r = 0; r < 4; ++r) {
    const int bt = r0 + r;
    float a0 = bb0, a1 = bb1;
    #pragma unroll
    for (int kz = 0; kz < KZ; ++kz) {
      unsigned int v = *(const unsigned int*)&part[(size_t)kz * (NB * TS * HID) + (size_t)bt * HID + h0];
      a0 += bf2f((unsigned short)(v & 0xffff));
      a1 += bf2f((unsigned short)(v >> 16));
    }
    a0 = fmaxf(a0, 0.f);
    a1 = fmaxf(a1, 0.f);
    float2 fo; fo.x = a0; fo.y = a1;
    *(float2*)&feat[(size_t)bt * HID + h0] = fo;
    fr[r][h0] = a0; fr[r][h0 + 1] = a1;
    float s0 = a0 * wa0 + a1 * wa3;
    float s1 = a0 * wa1 + a1 * wa4;
    float s2 = a0 * wa2 + a1 * wa5;
    #pragma unroll
    for (int off = 32; off; off >>= 1) {
      s0 += __shfl_xor(s0, off);
      s1 += __shfl_xor(s1, off);
      s2 += __shfl_xor(s2, off);
    }
    if (lane == 0) { sred[r][wv][0] = s0; sred[r][wv][1] = s1; sred[r][wv][2] = s2; }
  }
  __syncthreads();

  #pragma unroll
  for (int r = 0; r < 4; ++r) {
    const int bt = r0 + r;
    const int b = bt / TS, t = bt - b * TS;
    for (int c = wv; c < NC; c += 4) {
      float p = 0.f;
      #pragma unroll
      for (int i2 = 0; i2 < 8; ++i2) p += fr[r][lane + 64 * i2] * wc[c * HID + lane + 64 * i2];
      #pragma unroll
      for (int off = 32; off; off >>= 1) p += __shfl_xor(p, off);
      if (lane == 0) y_class[((size_t)b * NC + c) * TS + t] = p;
    }
  }
  if (tid < 4) {
    const int bt = r0 + tid;
    const int t = bt % TS;
    float S0 = sred[tid][0][0] + sred[tid][1][0] + sred[tid][2][0] + sred[tid][3][0];
    float S1 = sred[tid][0][1] + sred[tid][1][1] + sred[tid][2][1] + sred[tid][3][1];
    float S2 = sred[tid][0][2] + sred[tid][1][2] + sred[tid][2][2] + sred[tid][3][2];
    atomicAdd(&y_atn[bt], S1);
    if (t < TS - 1) atomicAdd(&y_atn[bt + 1], S0);
    if (t > 0)      atomicAdd(&y_atn[bt - 1], S2);
  }
}

// ---------- fused tail: bmn MFMA (y<3, W from global) + attention pooling fg (y==3) ----------
__global__ __launch_bounds__(256, 2) void k_tail(const float* __restrict__ y_class,
                                                 const unsigned short* __restrict__ WT,
                                                 const float* __restrict__ feat,
                                                 const float* __restrict__ y_atn,
                                                 const float* __restrict__ wc,
                                                 float* __restrict__ y_fg,
                                                 float* __restrict__ bmn) {
  __shared__ char Alds[64000];          // 160 rows x 400 B (Y bf16)
  const int tid = threadIdx.x;

  if (blockIdx.y == 3) {
    if (blockIdx.x >= NB) return;
    const int b = blockIdx.x;
    float* sig = (float*)Alds;
    float* red = sig + TS;
    float* xfg = red + 8;
    float s = 0.f;
    if (tid < TS) { s = 1.f / (1.f + expf(-y_atn[b * TS + tid])); sig[tid] = s; }
    float r = s;
    #pragma unroll
    for (int off = 32; off; off >>= 1) r += __shfl_xor(r, off);
    if ((tid & 63) == 0) red[tid >> 6] = r;
    __syncthreads();
    const float inv = 1.f / (red[0] + red[1] + red[2] + red[3] + 1e-8f);
    for (int h = tid; h < HID; h += 256) {
      float a = 0.f;
      for (int t = 0; t < TS; ++t) a += sig[t] * feat[((size_t)b * TS + t) * HID + h];
      xfg[h] = a * inv;
    }
    __syncthreads();
    const int wv = tid >> 6, lane = tid & 63;
    for (int c = wv; c < NC; c += 4) {
      float p = 0.f;
      #pragma unroll
      for (int i2 = 0; i2 < 8; ++i2) {
        int h = lane + 64 * i2;
        p += wc[c * HID + h] * xfg[h];
      }
      #pragma unroll
      for (int off = 32; off; off >>= 1) p += __shfl_xor(p, off);
      if (lane == 0) y_fg[b * NC + c] = p;
    }
    return;
  }

  // ---- bmn path: per-(i,g) 160x160x160 bf16 GEMM; W frags read direct from global (L2) ----
  const int i = blockIdx.x;
  const int g = blockIdx.y;
  const int wid = tid >> 6, lane = tid & 63;

  // stage A: read y_class f32 (L2-hot), cvt bf16, 400-B-stride rows
  const char* wtb = (const char*)WT + (size_t)g * 102400 + (size_t)(160 - i) * 320;
  for (int e = 0; e < 13; ++e) {
    const int ci = e * 256 + tid;
    if (ci < 3200) {
      const int row = ci / 20, c = ci - row * 20;
      const int tb = i + c * 8;
      const float* yr = y_class + (size_t)row * TS;
      unsigned short r8[8];
      #pragma unroll
      for (int k = 0; k < 8; ++k) {
        const int t = tb + k;
        r8[k] = (t < TS) ? f2bf(yr[t]) : (unsigned short)0;
      }
      *(uint4*)(Alds + (size_t)row * 400 + c * 16) = *(const uint4*)r8;
    }
  }
  __syncthreads();

  const int wr = wid >> 1, wcq = wid & 1;
  f32x4 acc[5][5] = {};

  #pragma unroll
  for (int ks = 0; ks < 5; ++ks) {
    const int cc = ks * 4 + (lane >> 4);
    bfrag bfr[5];
    #pragma unroll
    for (int nf = 0; nf < 5; ++nf) {
      const int j = wcq * 80 + nf * 16 + (lane & 15);
      bfr[nf] = *(const bfrag*)(wtb + (size_t)j * 320 + cc * 16);
    }
    #pragma unroll
    for (int mf = 0; mf < 5; ++mf) {
      const int r = wr * 80 + mf * 16 + (lane & 15);
      bfrag af = *(const bfrag*)(Alds + (size_t)r * 400 + cc * 16);
      #pragma unroll
      for (int nf = 0; nf < 5; ++nf)
        acc[mf][nf] = __builtin_amdgcn_mfma_f32_16x16x32_bf16(af, bfr[nf], acc[mf][nf], 0, 0, 0);
    }
  }

  #pragma unroll
  for (int mf = 0; mf < 5; ++mf) {
    const int r0 = wr * 80 + mf * 16 + (lane >> 4) * 4;
    #pragma unroll
    for (int reg = 0; reg < 4; ++reg) {
      const int r = r0 + reg;
      const int b = r / 20, c = r - b * 20;
      float* base = bmn + (((size_t)(b * 60 + g * 20 + c) * TS) + i) * TS;
      #pragma unroll
      for (int nf = 0; nf < 5; ++nf) {
        const int j = wcq * 80 + nf * 16 + (lane & 15);
        base[j] = acc[mf][nf][reg];
      }
    }
  }
}

extern "C" void kernel_launch(void* const* d_in, const int* in_sizes, int n_in,
                              void* d_out, int out_size, void* d_ws, size_t ws_size,
                              hipStream_t stream) {
  const float* x  = (const float*)d_in[0];
  const float* w1 = (const float*)d_in[2];
  const float* b1 = (const float*)d_in[3];
  const float* wc = (const float*)d_in[4];
  const float* wa = (const float*)d_in[5];
  const float* ba = (const float*)d_in[6];

  float* out     = (float*)d_out;
  float* y_class = out;                            // [8,20,160]
  float* y_fg    = out + NB * NC * TS;             // [8,20,1]
  float* bmn     = out + NB * NC * TS + NB * NC;   // [8,60,160,160]

  unsigned short* part = (unsigned short*)d_ws;                       // KZ*1280*512 bf16
  float* feat  = (float*)((char*)d_ws + (size_t)KZ * NB * TS * HID * 2);  // 1280*512 f32
  float* y_atn = feat + NB * TS * HID;                                // 1280 f32 (pad 2048)
  unsigned short* xb = (unsigned short*)(y_atn + 2048);               // 8*162*2048 bf16
  unsigned short* wb = xb + (size_t)NB * 162 * FEATD;                 // 3*512*2048 bf16
  unsigned short* WT = wb + (size_t)3 * HID * FEATD;                  // 3*320*160 bf16

  k_prep<<<2413, 256, 0, stream>>>(x, w1, ba, xb, wb, WT, y_atn);
  k_conv_mfma<<<dim3(8, 4, KZ), 256, 0, stream>>>(xb, wb, part);
  k_feat_head<<<NB * TS / 4, 256, 0, stream>>>(part, b1, wc, wa, feat, y_class, y_atn);
  k_tail<<<dim3(160, 4), 256, 0, stream>>>(y_class, WT, feat, y_atn, wc, y_fg, bmn);
}